// Round 3
// baseline (3593.333 us; speedup 1.0000x reference)
//
#include <hip/hip_runtime.h>

#define Bn 256
#define Tn 2048
#define Dn 40
#define Hn 128
#define Cn 35

typedef _Float16 h2 __attribute__((ext_vector_type(2)));

__device__ __forceinline__ float fdot2f(h2 a, h2 b, float c) {
#if __has_builtin(__builtin_amdgcn_fdot2)
  return __builtin_amdgcn_fdot2(a, b, c, false);
#else
  return c + (float)(a[0]) * (float)(b[0]) + (float)(a[1]) * (float)(b[1]);
#endif
}

__device__ __forceinline__ h2 pk2(float a, float b) {
  h2 r; r[0] = (_Float16)a; r[1] = (_Float16)b; return r;
}

__device__ __forceinline__ h2 bch(unsigned u) { return __builtin_bit_cast(h2, u); }

// broadcast pair from lane `l` of a wave-resident int (v_readlane -> SGPR)
__device__ __forceinline__ h2 bcast(int v, int l) {
  return __builtin_bit_cast(h2, __builtin_amdgcn_readlane(v, l));
}

__device__ __forceinline__ float rcpf_(float x) {
#if __has_builtin(__builtin_amdgcn_rcpf)
  return __builtin_amdgcn_rcpf(x);
#else
  return 1.f / x;
#endif
}

__device__ __forceinline__ float sigm(float v) {
  v = fmaxf(fminf(v, 60.f), -60.f);
  return rcpf_(1.f + __expf(-v));
}

__device__ __forceinline__ float tanha(float v) {
  v = fmaxf(fminf(v, 15.f), -15.f);
  const float e = __expf(2.f * v);
  return (e - 1.f) * rcpf_(e + 1.f);
}

// One WG (1024 threads) per batch element. Gate column `col = tid&511` of
// BOTH layers is owned by TWO threads (half = tid>>9), each holding half the
// K-range of the weights: 96 reg pairs/thread — fits the empirically-enforced
// 128-VGPR cap (512-thr rounds allocated 128 + 93MB spill traffic twice).
// w0x (10 pairs) lives in LDS (SoA uint2, conflict-free stride-1).
// Step = { P1: U-updates (thr<256) + x-dot2(t+1, all) + x staging | barrier |
//          P2: h-readlane dot2 stream -> partials s_p0/s_p1 | barrier }.
// U sums the two half-partials. h broadcast via v_readlane (VALU), not the
// LDS return bus (round-1 bottleneck). One h0 readlane feeds w0h AND w1x.
__global__ __launch_bounds__(1024) void lstm2_fused(
    const float* __restrict__ x,
    const int*   __restrict__ length,
    const float* __restrict__ Wih0, const float* __restrict__ Whh0,
    const float* __restrict__ bih0, const float* __restrict__ bhh0,
    const float* __restrict__ Wih1, const float* __restrict__ Whh1,
    const float* __restrict__ bih1, const float* __restrict__ bhh1,
    const float* __restrict__ gam,  const float* __restrict__ bet,
    const float* __restrict__ fcw,  const float* __restrict__ fcb,
    float* __restrict__ out)
{
  __shared__ __align__(16) uint2 s_w0x[5][1024];   // 40 KiB: w0x pair-pairs, SoA
  __shared__ __align__(16) h2 s_x[2][16][20];      // 2.5 KiB: double-buffered x chunks
  __shared__ __align__(16) h2 s_h0[64];
  __shared__ __align__(16) h2 s_h1[64];
  __shared__ float s_p0[1024];                     // g0 half-partials
  __shared__ float s_p1[1024];                     // g1 half-partials
  __shared__ float s_h1f[128];
  __shared__ float s_hn[128];

  const int tid  = threadIdx.x;
  const int lane = tid & 63;
  const int col  = tid & 511;
  const int half = tid >> 9;
  const int b    = blockIdx.x;
  const int len  = length[b];  // 1..2048

  // ---- register-resident weight halves (packed f16 pairs), K-split ----
  h2 w0h[32]; h2 w1x[32]; h2 w1h[32];
  {
    const float* p = Whh0 + col * Hn + 64 * half;
#pragma unroll
    for (int j = 0; j < 32; ++j) w0h[j] = pk2(p[2 * j], p[2 * j + 1]);
  }
  {
    const float* p = Wih1 + col * Hn + 64 * half;
#pragma unroll
    for (int j = 0; j < 32; ++j) w1x[j] = pk2(p[2 * j], p[2 * j + 1]);
  }
  {
    const float* p = Whh1 + col * Hn + 64 * half;
#pragma unroll
    for (int j = 0; j < 32; ++j) w1h[j] = pk2(p[2 * j], p[2 * j + 1]);
  }
  // w0x half -> LDS SoA: uint2 k holds pairs (2k,2k+1) = elems 20h+4k..+3
  {
    const float* p = Wih0 + col * Dn + 20 * half;
#pragma unroll
    for (int k = 0; k < 5; ++k) {
      uint2 v;
      v.x = __builtin_bit_cast(unsigned, pk2(p[4 * k],     p[4 * k + 1]));
      v.y = __builtin_bit_cast(unsigned, pk2(p[4 * k + 2], p[4 * k + 3]));
      s_w0x[k][tid] = v;
    }
  }
  const float bias0 = bih0[col] + bhh0[col];
  const float bias1 = bih1[col] + bhh1[col];

  float c0 = 0.f;  // threads 0..127   : L0 cell state
  float c1 = 0.f;  // threads 128..255 : L1 cell state

  if (tid < 64) {
    ((int*)s_h0)[tid] = 0;
    ((int*)s_h1)[tid] = 0;
  }
  // stage x chunk 0 (rows 0..15) into buf 0
  if (tid < 160) {
    const int r = tid / 10, q = tid - r * 10;
    const float4 v = *reinterpret_cast<const float4*>(
        x + ((size_t)b * Tn + (size_t)r) * Dn + 4 * q);
    s_x[0][r][2 * q]     = pk2(v.x, v.y);
    s_x[0][r][2 * q + 1] = pk2(v.z, v.w);
  }
  __syncthreads();

  // prologue: s_p0 = g0(0) half-partials (h0(-1)=0 so h-part is zero)
  {
    float a0 = half ? 0.f : bias0, a1 = 0.f;
    const uint2* xr = reinterpret_cast<const uint2*>(&s_x[0][0][0]) + 5 * half;
#pragma unroll
    for (int k = 0; k < 5; ++k) {
      const uint2 xv = xr[k];
      const uint2 wv = s_w0x[k][tid];
      a0 = fdot2f(bch(xv.x), bch(wv.x), a0);
      a1 = fdot2f(bch(xv.y), bch(wv.y), a1);
    }
    s_p0[tid] = a0 + a1;
  }
  __syncthreads();

  float4 xstage;  // pending x prefetch (threads 256..415)

#pragma unroll 1
  for (int t = 0; t < len; ++t) {
    // ---- P1: cell updates + x staging + x-dot2 for step t+1 ----
    if (tid < 128) {
      const float gi = s_p0[tid]       + s_p0[tid + 512];
      const float gf = s_p0[tid + 128] + s_p0[tid + 640];
      const float gg = s_p0[tid + 256] + s_p0[tid + 768];
      const float go = s_p0[tid + 384] + s_p0[tid + 896];
      c0 = sigm(gf) * c0 + sigm(gi) * tanha(gg);
      reinterpret_cast<_Float16*>(s_h0)[tid] = (_Float16)(sigm(go) * tanha(c0));
    } else if (tid < 256) {
      if (t > 0) {
        const int u = tid - 128;
        const float gi = s_p1[u]       + s_p1[u + 512];
        const float gf = s_p1[u + 128] + s_p1[u + 640];
        const float gg = s_p1[u + 256] + s_p1[u + 768];
        const float go = s_p1[u + 384] + s_p1[u + 896];
        c1 = sigm(gf) * c1 + sigm(gi) * tanha(gg);
        reinterpret_cast<_Float16*>(s_h1)[u] = (_Float16)(sigm(go) * tanha(c1));
      }
    } else if (tid < 416) {
      const int ph = t & 15;
      if (ph == 13) {
        // prefetch rows t+3 .. t+18 ((t+3) % 16 == 0), clamped
        const int u = tid - 256, r = u / 10, q = u - r * 10;
        int tr = t + 3 + r; if (tr > Tn - 1) tr = Tn - 1;
        xstage = *reinterpret_cast<const float4*>(
            x + ((size_t)b * Tn + (size_t)tr) * Dn + 4 * q);
      } else if (ph == 14) {
        // commit rows t+2..t+17 into buf ((t+2)>>4)&1; x-dot this phase
        // reads row t+1 (previous chunk, other buf) -> race-free
        const int u = tid - 256, r = u / 10, q = u - r * 10;
        h2* dst = &s_x[((t + 2) >> 4) & 1][r][0];
        dst[2 * q]     = pk2(xstage.x, xstage.y);
        dst[2 * q + 1] = pk2(xstage.z, xstage.w);
      }
    }
    // x-dot2 for step t+1 (all threads; accumulators carry into P2)
    float a0, a1;
    {
      const int row = (t + 1) & 15, buf = ((t + 1) >> 4) & 1;
      a0 = half ? 0.f : bias0; a1 = 0.f;
      const uint2* xr =
          reinterpret_cast<const uint2*>(&s_x[buf][row][0]) + 5 * half;
#pragma unroll
      for (int k = 0; k < 5; ++k) {
        const uint2 xv = xr[k];
        const uint2 wv = s_w0x[k][tid];
        a0 = fdot2f(bch(xv.x), bch(wv.x), a0);
        a1 = fdot2f(bch(xv.y), bch(wv.y), a1);
      }
    }
    __syncthreads();

    // ---- P2: h-dependent dot2 stream via readlane broadcast ----
    const int vh0 = ((const int*)s_h0)[32 * half + (lane & 31)];  // h0(t)
    const int vh1 = ((const int*)s_h1)[32 * half + (lane & 31)];  // h1(t-1)

    float b0 = half ? 0.f : bias1, b1 = 0.f;
#pragma unroll
    for (int j = 0; j < 32; j += 2) {
      const h2 p0 = bcast(vh0, j);
      const h2 p1 = bcast(vh0, j + 1);
      a0 = fdot2f(p0, w0h[j],     a0);
      b0 = fdot2f(p0, w1x[j],     b0);
      a1 = fdot2f(p1, w0h[j + 1], a1);
      b1 = fdot2f(p1, w1x[j + 1], b1);
    }
#pragma unroll
    for (int j = 0; j < 32; j += 2) {
      const h2 p0 = bcast(vh1, j);
      const h2 p1 = bcast(vh1, j + 1);
      b0 = fdot2f(p0, w1h[j],     b0);
      b1 = fdot2f(p1, w1h[j + 1], b1);
    }
    s_p0[tid] = a0 + a1;  // g0(t+1) half-partial
    s_p1[tid] = b0 + b1;  // g1(t)   half-partial
    __syncthreads();
  }

  // ---- epilogue: apply g1(len-1) (fp32) ----
  if (tid >= 128 && tid < 256) {
    const int u = tid - 128;
    const float gi = s_p1[u]       + s_p1[u + 512];
    const float gf = s_p1[u + 128] + s_p1[u + 640];
    const float gg = s_p1[u + 256] + s_p1[u + 768];
    const float go = s_p1[u + 384] + s_p1[u + 896];
    c1 = sigm(gf) * c1 + sigm(gi) * tanha(gg);
    s_h1f[u] = sigm(go) * tanha(c1);
  }
  __syncthreads();

  // ---- LayerNorm over H on wave 0 ----
  if (tid < 64) {
    const float a = s_h1f[tid], d = s_h1f[64 + tid];
    float s = a + d, q = a * a + d * d;
#pragma unroll
    for (int m = 32; m >= 1; m >>= 1) {
      s += __shfl_xor(s, m, 64);
      q += __shfl_xor(q, m, 64);
    }
    const float mu = s * (1.f / 128.f);
    float var = q * (1.f / 128.f) - mu * mu;
    var = fmaxf(var, 0.f);
    const float rstd = rsqrtf(var + 1e-5f);
    s_hn[tid]      = (a - mu) * rstd * gam[tid]      + bet[tid];
    s_hn[64 + tid] = (d - mu) * rstd * gam[64 + tid] + bet[64 + tid];
  }
  __syncthreads();

  // ---- FC head ----
  if (tid < Cn) {
    float acc = fcb[tid];
    const float* wp = fcw + tid * Hn;
#pragma unroll 4
    for (int k = 0; k < Hn; ++k) acc += s_hn[k] * wp[k];
    out[(size_t)b * Cn + tid] = acc;
  }
}

extern "C" void kernel_launch(void* const* d_in, const int* in_sizes, int n_in,
                              void* d_out, int out_size, void* d_ws, size_t ws_size,
                              hipStream_t stream) {
  (void)in_sizes; (void)n_in; (void)d_ws; (void)ws_size; (void)out_size;
  lstm2_fused<<<dim3(Bn), dim3(1024), 0, stream>>>(
      (const float*)d_in[0],  (const int*)d_in[1],
      (const float*)d_in[2],  (const float*)d_in[3],
      (const float*)d_in[4],  (const float*)d_in[5],
      (const float*)d_in[6],  (const float*)d_in[7],
      (const float*)d_in[8],  (const float*)d_in[9],
      (const float*)d_in[10], (const float*)d_in[11],
      (const float*)d_in[12], (const float*)d_in[13],
      (float*)d_out);
}

// Round 5
// 3227.431 us; speedup vs baseline: 1.1134x; 1.1134x over previous
//
#include <hip/hip_runtime.h>

#define Bn 256
#define Tn 2048
#define Dn 40
#define Hn 128
#define Cn 35

typedef _Float16 h2 __attribute__((ext_vector_type(2)));

__device__ __forceinline__ int sdot4(int a, int b, int c) {
#if __has_builtin(__builtin_amdgcn_sdot4)
  return __builtin_amdgcn_sdot4(a, b, c, false);
#else
  int r = c;
#pragma unroll
  for (int i = 0; i < 4; ++i)
    r += ((int)(a << (24 - 8 * i)) >> 24) * ((int)(b << (24 - 8 * i)) >> 24);
  return r;
#endif
}

__device__ __forceinline__ float fdot2f(h2 a, h2 b, float c) {
#if __has_builtin(__builtin_amdgcn_fdot2)
  return __builtin_amdgcn_fdot2(a, b, c, false);
#else
  return c + (float)(a[0]) * (float)(b[0]) + (float)(a[1]) * (float)(b[1]);
#endif
}

__device__ __forceinline__ h2 bch(int u) { return __builtin_bit_cast(h2, u); }

__device__ __forceinline__ int pk2i(float a, float b) {  // two f16 in one word
  h2 r; r[0] = (_Float16)a; r[1] = (_Float16)b;
  return __builtin_bit_cast(int, r);
}

__device__ __forceinline__ float rcpf_(float x) {
#if __has_builtin(__builtin_amdgcn_rcpf)
  return __builtin_amdgcn_rcpf(x);
#else
  return 1.f / x;
#endif
}

__device__ __forceinline__ float sigm(float v) {
  v = fmaxf(fminf(v, 60.f), -60.f);
  return rcpf_(1.f + __expf(-v));
}

__device__ __forceinline__ float tanha(float v) {
  v = fmaxf(fminf(v, 15.f), -15.f);
  const float e = __expf(2.f * v);
  return (e - 1.f) * rcpf_(e + 1.f);
}

__device__ __forceinline__ int q8c(float v) {  // round+clamp to [-127,127]
  v = fminf(fmaxf(v, -127.f), 127.f);
  return (int)__builtin_rintf(v);
}

__device__ __forceinline__ int pk4(int a, int b, int c, int d) {
  return (a & 255) | ((b & 255) << 8) | ((c & 255) << 16) | (d << 24);
}

#if __has_builtin(__builtin_amdgcn_global_load_lds)
#define HAVE_GLDS 1
__device__ __forceinline__ void gl_lds16(const float* g, float* l) {
  __builtin_amdgcn_global_load_lds(
      (const __attribute__((address_space(1))) unsigned int*)(const void*)g,
      (__attribute__((address_space(3))) unsigned int*)(void*)l, 16, 0, 0);
}
#endif

// quantize 128 f32 weights -> 32 packed-i8 words + scale (rowmax/127)
__device__ __forceinline__ void quantW128(const float* __restrict__ p,
                                          int* __restrict__ q, float& sc) {
  float m = 1e-30f;
#pragma unroll
  for (int i = 0; i < 32; ++i) {
    const float4 v = reinterpret_cast<const float4*>(p)[i];
    m = fmaxf(m, fmaxf(fmaxf(fabsf(v.x), fabsf(v.y)),
                       fmaxf(fabsf(v.z), fabsf(v.w))));
  }
  const float inv = 127.f / m;
  sc = m * (1.f / 127.f);
#pragma unroll
  for (int i = 0; i < 32; ++i) {
    const float4 v = reinterpret_cast<const float4*>(p)[i];
    q[i] = pk4(q8c(v.x * inv), q8c(v.y * inv), q8c(v.z * inv), q8c(v.w * inv));
  }
}

// readlane word w (0..319) from 5-reg stash (lane L holds flat[L+64k])
#define RLST(w) __builtin_amdgcn_readlane(                                  \
    ((w) < 64 ? st0 : (w) < 128 ? st1 : (w) < 192 ? st2 : (w) < 256 ? st3  \
                                                        : st4), (w) & 63)

// Register law (measured r1-r4): 65,536 VGPRs per WG total regardless of
// block shape -> 512 thr @ 128 regs. i8 weights for the 3 H-matrices (96
// regs/thread); x-path in f16 (w0x f16 in LDS, read only in the 16x-
// amortized projection burst). h quantized per step at dynamic scale
// 127/max|h| (max reduced in U phase), delivered via v_readlane (r1 showed
// LDS-broadcast delivery saturates the LDS return bus). r4 bug fixed by
// construction: dequant = idot * w_scale * (hmax/127) — the h-scale factor
// is explicit.
__global__ __launch_bounds__(512) void lstm2_fused(
    const float* __restrict__ x,
    const int*   __restrict__ length,
    const float* __restrict__ Wih0, const float* __restrict__ Whh0,
    const float* __restrict__ bih0, const float* __restrict__ bhh0,
    const float* __restrict__ Wih1, const float* __restrict__ Whh1,
    const float* __restrict__ bih1, const float* __restrict__ bhh1,
    const float* __restrict__ gam,  const float* __restrict__ bet,
    const float* __restrict__ fcw,  const float* __restrict__ fcb,
    float* __restrict__ out)
{
  __shared__ int   s_w0x[20][512];                 // 40 KiB w0x f16-pairs SoA
  __shared__ __align__(16) float s_xraw[192 * 4];  // 3 KiB raw x chunk (glds dest)
  __shared__ int   s_xh2[2][320];                  // 2.5 KiB f16 x chunks
  __shared__ float s_xp[2][16][512];               // 64 KiB x-projection
  __shared__ float s_p0[4][132];                   // g0 gates
  __shared__ float s_p1[4][132];                   // g1 gates
  __shared__ __align__(16) float s_h0f[128];
  __shared__ __align__(16) float s_h1f[128];
  __shared__ float s_hn[128];
  __shared__ float s_red[4];                       // per-wave |h| maxes

  const int tid  = threadIdx.x;
  const int lane = tid & 63;
  const int b    = blockIdx.x;
  const int len  = length[b];  // 1..2048

  // ---- kick off chunk-0 x prefetch (hidden under weight setup) ----
  if (tid >= 256 && tid < 448) {
    const int seg0 = (tid >> 6) - 4;  // wave segment 0..2
    int seg = seg0 * 64 + lane;
    if (seg >= 160) seg = 0;  // clamp (writes land in unused s_xraw tail)
#if HAVE_GLDS
    gl_lds16(x + (size_t)b * Tn * Dn + seg * 4, &s_xraw[seg0 * 256]);
#else
    *(float4*)&s_xraw[seg * 4] =
        *(const float4*)(x + (size_t)b * Tn * Dn + seg * 4);
#endif
  }

  // ---- weight setup ----
  int q0h[32], q1x[32], q1h[32];
  float s0h, s1x, s1h;
  quantW128(Whh0 + (size_t)tid * Hn, q0h, s0h);
  quantW128(Wih1 + (size_t)tid * Hn, q1x, s1x);
  quantW128(Whh1 + (size_t)tid * Hn, q1h, s1h);
  {  // w0x -> LDS as f16 pairs (SoA word k = elems 2k,2k+1 of this column)
    const float* p = Wih0 + (size_t)tid * Dn;
#pragma unroll
    for (int k = 0; k < 20; ++k) s_w0x[k][tid] = pk2i(p[2 * k], p[2 * k + 1]);
  }
  const float bias0 = bih0[tid] + bhh0[tid];
  const float bias1 = bih1[tid] + bhh1[tid];

  float c0 = 0.f;  // threads 0..127   : L0 cell
  float c1 = 0.f;  // threads 128..255 : L1 cell

  if (tid < 128) s_h0f[tid] = 0.f;
  else if (tid < 256) s_h1f[tid - 128] = 0.f;
  __syncthreads();  // glds drained; s_w0x/s_xraw visible

  // x-projection burst: s_xh2[bb] -> s_xp[bb] (4 passes x 4 rows caps regs)
  auto burst = [&](int bb) {
    const int* flat = &s_xh2[bb][0];
    const int st0 = flat[lane], st1 = flat[lane + 64], st2 = flat[lane + 128],
              st3 = flat[lane + 192], st4 = flat[lane + 256];
#pragma unroll
    for (int pass = 0; pass < 4; ++pass) {
      float a0 = 0.f, a1 = 0.f, a2 = 0.f, a3 = 0.f;
      const int r0 = pass * 4;
#pragma unroll
      for (int g = 0; g < 5; ++g) {
        const h2 w0 = bch(s_w0x[4 * g + 0][tid]);
        const h2 w1 = bch(s_w0x[4 * g + 1][tid]);
        const h2 w2 = bch(s_w0x[4 * g + 2][tid]);
        const h2 w3 = bch(s_w0x[4 * g + 3][tid]);
        a0 = fdot2f(bch(RLST(20 * (r0 + 0) + 4 * g + 0)), w0, a0);
        a0 = fdot2f(bch(RLST(20 * (r0 + 0) + 4 * g + 1)), w1, a0);
        a0 = fdot2f(bch(RLST(20 * (r0 + 0) + 4 * g + 2)), w2, a0);
        a0 = fdot2f(bch(RLST(20 * (r0 + 0) + 4 * g + 3)), w3, a0);
        a1 = fdot2f(bch(RLST(20 * (r0 + 1) + 4 * g + 0)), w0, a1);
        a1 = fdot2f(bch(RLST(20 * (r0 + 1) + 4 * g + 1)), w1, a1);
        a1 = fdot2f(bch(RLST(20 * (r0 + 1) + 4 * g + 2)), w2, a1);
        a1 = fdot2f(bch(RLST(20 * (r0 + 1) + 4 * g + 3)), w3, a1);
        a2 = fdot2f(bch(RLST(20 * (r0 + 2) + 4 * g + 0)), w0, a2);
        a2 = fdot2f(bch(RLST(20 * (r0 + 2) + 4 * g + 1)), w1, a2);
        a2 = fdot2f(bch(RLST(20 * (r0 + 2) + 4 * g + 2)), w2, a2);
        a2 = fdot2f(bch(RLST(20 * (r0 + 2) + 4 * g + 3)), w3, a2);
        a3 = fdot2f(bch(RLST(20 * (r0 + 3) + 4 * g + 0)), w0, a3);
        a3 = fdot2f(bch(RLST(20 * (r0 + 3) + 4 * g + 1)), w1, a3);
        a3 = fdot2f(bch(RLST(20 * (r0 + 3) + 4 * g + 2)), w2, a3);
        a3 = fdot2f(bch(RLST(20 * (r0 + 3) + 4 * g + 3)), w3, a3);
      }
      s_xp[bb][r0 + 0][tid] = a0;
      s_xp[bb][r0 + 1][tid] = a1;
      s_xp[bb][r0 + 2][tid] = a2;
      s_xp[bb][r0 + 3][tid] = a3;
    }
  };

  // ---- chunk 0: convert to f16, project ----
  if (tid >= 256 && tid < 416) {
    const int u = tid - 256;  // 0..159
    const float4 v = *(const float4*)&s_xraw[4 * u];
    s_xh2[0][2 * u]     = pk2i(v.x, v.y);
    s_xh2[0][2 * u + 1] = pk2i(v.z, v.w);
  }
  __syncthreads();
  burst(0);
  __syncthreads();
  s_p0[tid >> 7][tid & 127] = bias0 + s_xp[0][0][tid];  // g0(0), h0(-1)=0
  __syncthreads();

#pragma unroll 1
  for (int t = 0; t < len; ++t) {
    const int tl = t & 15;

    // ---------- U phase: cell updates + |h| max reduce + x convert ----------
    if (tid < 128) {
      const float gi = s_p0[0][tid], gf = s_p0[1][tid];
      const float gg = s_p0[2][tid], go = s_p0[3][tid];
      c0 = sigm(gf) * c0 + sigm(gi) * tanha(gg);
      const float h = sigm(go) * tanha(c0);
      s_h0f[tid] = h;
      float m = fabsf(h);
#pragma unroll
      for (int k = 32; k >= 1; k >>= 1) m = fmaxf(m, __shfl_xor(m, k, 64));
      if ((tid & 63) == 0) s_red[tid >> 6] = m;
    } else if (tid < 256) {
      float m = 0.f;
      if (t > 0) {
        const int u = tid - 128;
        const float gi = s_p1[0][u], gf = s_p1[1][u];
        const float gg = s_p1[2][u], go = s_p1[3][u];
        c1 = sigm(gf) * c1 + sigm(gi) * tanha(gg);
        const float h = sigm(go) * tanha(c1);
        s_h1f[u] = h;
        m = fabsf(h);
      }
#pragma unroll
      for (int k = 32; k >= 1; k >>= 1) m = fmaxf(m, __shfl_xor(m, k, 64));
      if ((tid & 63) == 0) s_red[tid >> 6] = m;
    } else if (tid < 416 && tl == 13) {
      // convert raw chunk (rows t+3 .. t+18) -> f16 chunk buffer
      const int u = tid - 256;
      const float4 v = *(const float4*)&s_xraw[4 * u];
      const int nb = ((t + 3) >> 4) & 1;
      s_xh2[nb][2 * u]     = pk2i(v.x, v.y);
      s_xh2[nb][2 * u + 1] = pk2i(v.z, v.w);
    }
    __syncthreads();

    // ---------- DOT phase ----------
    if (tid >= 256 && tid < 448 && tl == 12) {  // async prefetch next raw x
      const int t0 = (t & ~15) + 16;
      if (t0 <= Tn - 16) {
        const int seg0 = (tid >> 6) - 4;
        int seg = seg0 * 64 + lane;
        if (seg >= 160) seg = 0;
#if HAVE_GLDS
        gl_lds16(x + ((size_t)b * Tn + t0) * Dn + seg * 4,
                 &s_xraw[seg0 * 256]);
#else
        *(float4*)&s_xraw[seg * 4] =
            *(const float4*)(x + ((size_t)b * Tn + t0) * Dn + seg * 4);
#endif
      }
    }

    const float hm0 = fmaxf(fmaxf(s_red[0], s_red[1]), 1e-12f);
    const float hm1 = fmaxf(fmaxf(s_red[2], s_red[3]), 1e-12f);
    const float inv0 = 127.f * rcpf_(hm0), inv1 = 127.f * rcpf_(hm1);

    // pack h0(t) (lanes 0-31) / h1(t-1) (lanes 32-63) as i8x4 @ dynamic scale
    int vq;
    {
      const float4 hv = (lane < 32) ? *(const float4*)&s_h0f[4 * lane]
                                    : *(const float4*)&s_h1f[4 * (lane - 32)];
      const float inv = (lane < 32) ? inv0 : inv1;
      vq = pk4((int)__builtin_rintf(hv.x * inv), (int)__builtin_rintf(hv.y * inv),
               (int)__builtin_rintf(hv.z * inv), (int)__builtin_rintf(hv.w * inv));
    }

    const int rowi = t + 1;
    const float xacc = s_xp[(rowi >> 4) & 1][rowi & 15][tid];

    int ia = 0, ia2 = 0, ib = 0, ib2 = 0, ic = 0, ic2 = 0;
#pragma unroll
    for (int j = 0; j < 32; j += 2) {  // h0 -> w0h (g0) and w1x (g1)
      const int s0 = __builtin_amdgcn_readlane(vq, j);
      const int s1 = __builtin_amdgcn_readlane(vq, j + 1);
      ia  = sdot4(s0, q0h[j], ia);
      ib  = sdot4(s0, q1x[j], ib);
      ia2 = sdot4(s1, q0h[j + 1], ia2);
      ib2 = sdot4(s1, q1x[j + 1], ib2);
    }
#pragma unroll
    for (int j = 0; j < 32; j += 2) {  // h1 -> w1h (g1)
      const int s0 = __builtin_amdgcn_readlane(vq, 32 + j);
      const int s1 = __builtin_amdgcn_readlane(vq, 33 + j);
      ic  = sdot4(s0, q1h[j], ic);
      ic2 = sdot4(s1, q1h[j + 1], ic2);
    }
    const float f0 = hm0 * (1.f / 127.f), f1 = hm1 * (1.f / 127.f);
    s_p0[tid >> 7][tid & 127] =
        bias0 + xacc + (float)(ia + ia2) * (s0h * f0);
    s_p1[tid >> 7][tid & 127] =
        bias1 + (float)(ib + ib2) * (s1x * f0) + (float)(ic + ic2) * (s1h * f1);

    if (tl == 14) burst(((t + 2) >> 4) & 1);  // project next chunk (1/16)
    __syncthreads();
  }

  // ---- epilogue: apply g1(len-1) -> h1 (fp32) ----
  if (tid >= 128 && tid < 256) {
    const int u = tid - 128;
    const float gi = s_p1[0][u], gf = s_p1[1][u];
    const float gg = s_p1[2][u], go = s_p1[3][u];
    c1 = sigm(gf) * c1 + sigm(gi) * tanha(gg);
    s_h1f[u] = sigm(go) * tanha(c1);
  }
  __syncthreads();

  // ---- LayerNorm over H on wave 0 ----
  if (tid < 64) {
    const float a = s_h1f[tid], d = s_h1f[64 + tid];
    float s = a + d, q = a * a + d * d;
#pragma unroll
    for (int m = 32; m >= 1; m >>= 1) {
      s += __shfl_xor(s, m, 64);
      q += __shfl_xor(q, m, 64);
    }
    const float mu = s * (1.f / 128.f);
    float var = q * (1.f / 128.f) - mu * mu;
    var = fmaxf(var, 0.f);
    const float rstd = rsqrtf(var + 1e-5f);
    s_hn[tid]      = (a - mu) * rstd * gam[tid]      + bet[tid];
    s_hn[64 + tid] = (d - mu) * rstd * gam[64 + tid] + bet[64 + tid];
  }
  __syncthreads();

  // ---- FC head ----
  if (tid < Cn) {
    float acc = fcb[tid];
    const float* wp = fcw + tid * Hn;
#pragma unroll 4
    for (int k = 0; k < Hn; ++k) acc += s_hn[k] * wp[k];
    out[(size_t)b * Cn + tid] = acc;
  }
}

extern "C" void kernel_launch(void* const* d_in, const int* in_sizes, int n_in,
                              void* d_out, int out_size, void* d_ws, size_t ws_size,
                              hipStream_t stream) {
  (void)in_sizes; (void)n_in; (void)d_ws; (void)ws_size; (void)out_size;
  lstm2_fused<<<dim3(Bn), dim3(512), 0, stream>>>(
      (const float*)d_in[0],  (const int*)d_in[1],
      (const float*)d_in[2],  (const float*)d_in[3],
      (const float*)d_in[4],  (const float*)d_in[5],
      (const float*)d_in[6],  (const float*)d_in[7],
      (const float*)d_in[8],  (const float*)d_in[9],
      (const float*)d_in[10], (const float*)d_in[11],
      (const float*)d_in[12], (const float*)d_in[13],
      (float*)d_out);
}

// Round 6
// 2510.435 us; speedup vs baseline: 1.4314x; 1.2856x over previous
//
#include <hip/hip_runtime.h>

#define Bn 256
#define Tn 2048
#define Dn 40
#define Hn 128
#define Cn 35

typedef _Float16 h2 __attribute__((ext_vector_type(2)));

__device__ __forceinline__ int sdot4(int a, int b, int c) {
#if __has_builtin(__builtin_amdgcn_sdot4)
  return __builtin_amdgcn_sdot4(a, b, c, false);
#else
  int r = c;
#pragma unroll
  for (int i = 0; i < 4; ++i)
    r += ((int)(a << (24 - 8 * i)) >> 24) * ((int)(b << (24 - 8 * i)) >> 24);
  return r;
#endif
}

__device__ __forceinline__ float fdot2f(h2 a, h2 b, float c) {
#if __has_builtin(__builtin_amdgcn_fdot2)
  return __builtin_amdgcn_fdot2(a, b, c, false);
#else
  return c + (float)(a[0]) * (float)(b[0]) + (float)(a[1]) * (float)(b[1]);
#endif
}

__device__ __forceinline__ h2 bch(int u) { return __builtin_bit_cast(h2, u); }

__device__ __forceinline__ int pk2i(float a, float b) {  // two f16 in one word
  h2 r; r[0] = (_Float16)a; r[1] = (_Float16)b;
  return __builtin_bit_cast(int, r);
}

__device__ __forceinline__ float rcpf_(float x) {
#if __has_builtin(__builtin_amdgcn_rcpf)
  return __builtin_amdgcn_rcpf(x);
#else
  return 1.f / x;
#endif
}

__device__ __forceinline__ float sigm(float v) {
  v = fmaxf(fminf(v, 60.f), -60.f);
  return rcpf_(1.f + __expf(-v));
}

__device__ __forceinline__ float tanha(float v) {
  v = fmaxf(fminf(v, 15.f), -15.f);
  const float e = __expf(2.f * v);
  return (e - 1.f) * rcpf_(e + 1.f);
}

__device__ __forceinline__ int q8c(float v) {  // round+clamp to [-127,127]
  v = fminf(fmaxf(v, -127.f), 127.f);
  return (int)__builtin_rintf(v);
}

__device__ __forceinline__ int pk4(int a, int b, int c, int d) {
  return (a & 255) | ((b & 255) << 8) | ((c & 255) << 16) | (d << 24);
}

#if __has_builtin(__builtin_amdgcn_global_load_lds)
#define HAVE_GLDS 1
__device__ __forceinline__ void gl_lds16(const float* g, float* l) {
  __builtin_amdgcn_global_load_lds(
      (const __attribute__((address_space(1))) unsigned int*)(const void*)g,
      (__attribute__((address_space(3))) unsigned int*)(void*)l, 16, 0, 0);
}
#endif

// quantize 128 f32 weights -> 32 packed-i8 words + scale (rowmax/127)
__device__ __forceinline__ void quantW128(const float* __restrict__ p,
                                          int* __restrict__ q, float& sc) {
  float m = 1e-30f;
#pragma unroll
  for (int i = 0; i < 32; ++i) {
    const float4 v = reinterpret_cast<const float4*>(p)[i];
    m = fmaxf(m, fmaxf(fmaxf(fabsf(v.x), fabsf(v.y)),
                       fmaxf(fabsf(v.z), fabsf(v.w))));
  }
  const float inv = 127.f / m;
  sc = m * (1.f / 127.f);
#pragma unroll
  for (int i = 0; i < 32; ++i) {
    const float4 v = reinterpret_cast<const float4*>(p)[i];
    q[i] = pk4(q8c(v.x * inv), q8c(v.y * inv), q8c(v.z * inv), q8c(v.w * inv));
  }
}

// readlane word w (0..319) from 5-reg stash (lane L holds flat[L+64k])
#define RLST(w) __builtin_amdgcn_readlane(                                  \
    ((w) < 64 ? st0 : (w) < 128 ? st1 : (w) < 192 ? st2 : (w) < 256 ? st3  \
                                                        : st4), (w) & 63)

// r1-r5 law #1: 65,536 VGPRs per WG total (any block shape) -> i8 weights.
// r1-r5 law #2: all skeletons with {LDS round trips + shfl-max + 2-3
// barriers} hit the same ~3700 cy/step latency floor (VALUBusy 32% => the
// step is chain-bound, not issue-bound). r6 cuts the chain: fixed h-scale
// (127; h in (-1,1)) kills the 6-deep shfl-max + s_red + rcp; U threads
// emit packed i8 h via ds_write_b8 so DOT fetches its readlane stash with
// ONE ds_read_b32 (no float4 read, no rint/pk4); dequant scales folded at
// setup. Chain: gates(120) -> update(~80) -> b8 write -> bar -> stash(120)
// -> dot(~640 issue) -> bar  ~= 1300 cy/step.
__global__ __launch_bounds__(512) void lstm2_fused(
    const float* __restrict__ x,
    const int*   __restrict__ length,
    const float* __restrict__ Wih0, const float* __restrict__ Whh0,
    const float* __restrict__ bih0, const float* __restrict__ bhh0,
    const float* __restrict__ Wih1, const float* __restrict__ Whh1,
    const float* __restrict__ bih1, const float* __restrict__ bhh1,
    const float* __restrict__ gam,  const float* __restrict__ bet,
    const float* __restrict__ fcw,  const float* __restrict__ fcb,
    float* __restrict__ out)
{
  __shared__ int   s_w0x[20][512];                 // 40 KiB w0x f16-pairs SoA
  __shared__ __align__(16) float s_xraw[192 * 4];  // 3 KiB raw x chunk (glds dest)
  __shared__ int   s_xh2[2][320];                  // 2.5 KiB f16 x chunks
  __shared__ float s_xp[2][16][512];               // 64 KiB x-projection
  __shared__ float s_p0[4][132];                   // g0 gates
  __shared__ float s_p1[4][132];                   // g1 gates
  __shared__ int   s_hq[64];                       // packed i8 h0|h1 (words 0-31|32-63)
  __shared__ float s_h1f[128];
  __shared__ float s_hn[128];

  const int tid  = threadIdx.x;
  const int lane = tid & 63;
  const int b    = blockIdx.x;
  const int len  = length[b];  // 1..2048

  // ---- kick off chunk-0 x prefetch (hidden under weight setup) ----
  if (tid >= 256 && tid < 448) {
    const int seg0 = (tid >> 6) - 4;  // wave segment 0..2
    int seg = seg0 * 64 + lane;
    if (seg >= 160) seg = 0;  // clamp (writes land in unused s_xraw tail)
#if HAVE_GLDS
    gl_lds16(x + (size_t)b * Tn * Dn + seg * 4, &s_xraw[seg0 * 256]);
#else
    *(float4*)&s_xraw[seg * 4] =
        *(const float4*)(x + (size_t)b * Tn * Dn + seg * 4);
#endif
  }

  // ---- weight setup ----
  int q0h[32], q1x[32], q1h[32];
  float s0h, s1x, s1h;
  quantW128(Whh0 + (size_t)tid * Hn, q0h, s0h);
  quantW128(Wih1 + (size_t)tid * Hn, q1x, s1x);
  quantW128(Whh1 + (size_t)tid * Hn, q1h, s1h);
  s0h *= (1.f / 127.f);  // fold fixed h-scale into dequant factors
  s1x *= (1.f / 127.f);
  s1h *= (1.f / 127.f);
  {  // w0x -> LDS as f16 pairs (SoA word k = elems 2k,2k+1 of this column)
    const float* p = Wih0 + (size_t)tid * Dn;
#pragma unroll
    for (int k = 0; k < 20; ++k) s_w0x[k][tid] = pk2i(p[2 * k], p[2 * k + 1]);
  }
  const float bias0 = bih0[tid] + bhh0[tid];
  const float bias1 = bih1[tid] + bhh1[tid];

  float c0 = 0.f;  // threads 0..127   : L0 cell
  float c1 = 0.f;  // threads 128..255 : L1 cell

  if (tid < 64) s_hq[tid] = 0;  // h0(-1)=h1(-1)=0
  __syncthreads();  // glds drained; s_w0x/s_xraw visible

  // x-projection burst: s_xh2[bb] -> s_xp[bb] (4 passes x 4 rows caps regs)
  auto burst = [&](int bb) {
    const int* flat = &s_xh2[bb][0];
    const int st0 = flat[lane], st1 = flat[lane + 64], st2 = flat[lane + 128],
              st3 = flat[lane + 192], st4 = flat[lane + 256];
#pragma unroll
    for (int pass = 0; pass < 4; ++pass) {
      float a0 = 0.f, a1 = 0.f, a2 = 0.f, a3 = 0.f;
      const int r0 = pass * 4;
#pragma unroll
      for (int g = 0; g < 5; ++g) {
        const h2 w0 = bch(s_w0x[4 * g + 0][tid]);
        const h2 w1 = bch(s_w0x[4 * g + 1][tid]);
        const h2 w2 = bch(s_w0x[4 * g + 2][tid]);
        const h2 w3 = bch(s_w0x[4 * g + 3][tid]);
        a0 = fdot2f(bch(RLST(20 * (r0 + 0) + 4 * g + 0)), w0, a0);
        a0 = fdot2f(bch(RLST(20 * (r0 + 0) + 4 * g + 1)), w1, a0);
        a0 = fdot2f(bch(RLST(20 * (r0 + 0) + 4 * g + 2)), w2, a0);
        a0 = fdot2f(bch(RLST(20 * (r0 + 0) + 4 * g + 3)), w3, a0);
        a1 = fdot2f(bch(RLST(20 * (r0 + 1) + 4 * g + 0)), w0, a1);
        a1 = fdot2f(bch(RLST(20 * (r0 + 1) + 4 * g + 1)), w1, a1);
        a1 = fdot2f(bch(RLST(20 * (r0 + 1) + 4 * g + 2)), w2, a1);
        a1 = fdot2f(bch(RLST(20 * (r0 + 1) + 4 * g + 3)), w3, a1);
        a2 = fdot2f(bch(RLST(20 * (r0 + 2) + 4 * g + 0)), w0, a2);
        a2 = fdot2f(bch(RLST(20 * (r0 + 2) + 4 * g + 1)), w1, a2);
        a2 = fdot2f(bch(RLST(20 * (r0 + 2) + 4 * g + 2)), w2, a2);
        a2 = fdot2f(bch(RLST(20 * (r0 + 2) + 4 * g + 3)), w3, a2);
        a3 = fdot2f(bch(RLST(20 * (r0 + 3) + 4 * g + 0)), w0, a3);
        a3 = fdot2f(bch(RLST(20 * (r0 + 3) + 4 * g + 1)), w1, a3);
        a3 = fdot2f(bch(RLST(20 * (r0 + 3) + 4 * g + 2)), w2, a3);
        a3 = fdot2f(bch(RLST(20 * (r0 + 3) + 4 * g + 3)), w3, a3);
      }
      s_xp[bb][r0 + 0][tid] = a0;
      s_xp[bb][r0 + 1][tid] = a1;
      s_xp[bb][r0 + 2][tid] = a2;
      s_xp[bb][r0 + 3][tid] = a3;
    }
  };

  // ---- chunk 0: convert to f16, project ----
  if (tid >= 256 && tid < 416) {
    const int u = tid - 256;  // 0..159
    const float4 v = *(const float4*)&s_xraw[4 * u];
    s_xh2[0][2 * u]     = pk2i(v.x, v.y);
    s_xh2[0][2 * u + 1] = pk2i(v.z, v.w);
  }
  __syncthreads();
  burst(0);
  __syncthreads();
  s_p0[tid >> 7][tid & 127] = bias0 + s_xp[0][0][tid];  // g0(0), h0(-1)=0
  __syncthreads();

#pragma unroll 1
  for (int t = 0; t < len; ++t) {
    const int tl = t & 15;

    // ---------- U phase: cell updates -> packed i8 h via byte stores ----------
    if (tid < 128) {
      const float gi = s_p0[0][tid], gf = s_p0[1][tid];
      const float gg = s_p0[2][tid], go = s_p0[3][tid];
      c0 = sigm(gf) * c0 + sigm(gi) * tanha(gg);
      const float h = sigm(go) * tanha(c0);
      ((signed char*)s_hq)[tid] = (signed char)(int)__builtin_rintf(h * 127.f);
    } else if (tid < 256) {
      if (t > 0) {
        const int u = tid - 128;
        const float gi = s_p1[0][u], gf = s_p1[1][u];
        const float gg = s_p1[2][u], go = s_p1[3][u];
        c1 = sigm(gf) * c1 + sigm(gi) * tanha(gg);
        const float h = sigm(go) * tanha(c1);
        ((signed char*)s_hq)[128 + u] =
            (signed char)(int)__builtin_rintf(h * 127.f);
      }
    } else if (tid < 416 && tl == 13) {
      // convert raw chunk (rows t+3 .. t+18) -> f16 chunk buffer
      const int u = tid - 256;
      const float4 v = *(const float4*)&s_xraw[4 * u];
      const int nb = ((t + 3) >> 4) & 1;
      s_xh2[nb][2 * u]     = pk2i(v.x, v.y);
      s_xh2[nb][2 * u + 1] = pk2i(v.z, v.w);
    }
    __syncthreads();

    // ---------- DOT phase ----------
    const int vq = s_hq[lane];  // stash word: h0 words 0-31, h1 words 32-63

    if (tid >= 256 && tid < 448 && tl == 12) {  // async prefetch next raw x
      const int t0 = (t & ~15) + 16;
      if (t0 <= Tn - 16) {
        const int seg0 = (tid >> 6) - 4;
        int seg = seg0 * 64 + lane;
        if (seg >= 160) seg = 0;
#if HAVE_GLDS
        gl_lds16(x + ((size_t)b * Tn + t0) * Dn + seg * 4,
                 &s_xraw[seg0 * 256]);
#else
        *(float4*)&s_xraw[seg * 4] =
            *(const float4*)(x + ((size_t)b * Tn + t0) * Dn + seg * 4);
#endif
      }
    }

    const int rowi = t + 1;
    const float xacc = s_xp[(rowi >> 4) & 1][rowi & 15][tid];

    int ia = 0, ia2 = 0, ib = 0, ib2 = 0, ic = 0, ic2 = 0;
#pragma unroll
    for (int j = 0; j < 32; j += 2) {  // h0 -> w0h (g0) and w1x (g1)
      const int s0 = __builtin_amdgcn_readlane(vq, j);
      const int s1 = __builtin_amdgcn_readlane(vq, j + 1);
      ia  = sdot4(s0, q0h[j], ia);
      ib  = sdot4(s0, q1x[j], ib);
      ia2 = sdot4(s1, q0h[j + 1], ia2);
      ib2 = sdot4(s1, q1x[j + 1], ib2);
    }
#pragma unroll
    for (int j = 0; j < 32; j += 2) {  // h1 -> w1h (g1)
      const int s0 = __builtin_amdgcn_readlane(vq, 32 + j);
      const int s1 = __builtin_amdgcn_readlane(vq, 33 + j);
      ic  = sdot4(s0, q1h[j], ic);
      ic2 = sdot4(s1, q1h[j + 1], ic2);
    }
    s_p0[tid >> 7][tid & 127] = bias0 + xacc + (float)(ia + ia2) * s0h;
    s_p1[tid >> 7][tid & 127] =
        bias1 + (float)(ib + ib2) * s1x + (float)(ic + ic2) * s1h;

    if (tl == 14) burst(((t + 2) >> 4) & 1);  // project next chunk (1/16)
    __syncthreads();
  }

  // ---- epilogue: apply g1(len-1) -> h1 (fp32) ----
  if (tid >= 128 && tid < 256) {
    const int u = tid - 128;
    const float gi = s_p1[0][u], gf = s_p1[1][u];
    const float gg = s_p1[2][u], go = s_p1[3][u];
    c1 = sigm(gf) * c1 + sigm(gi) * tanha(gg);
    s_h1f[u] = sigm(go) * tanha(c1);
  }
  __syncthreads();

  // ---- LayerNorm over H on wave 0 ----
  if (tid < 64) {
    const float a = s_h1f[tid], d = s_h1f[64 + tid];
    float s = a + d, q = a * a + d * d;
#pragma unroll
    for (int m = 32; m >= 1; m >>= 1) {
      s += __shfl_xor(s, m, 64);
      q += __shfl_xor(q, m, 64);
    }
    const float mu = s * (1.f / 128.f);
    float var = q * (1.f / 128.f) - mu * mu;
    var = fmaxf(var, 0.f);
    const float rstd = rsqrtf(var + 1e-5f);
    s_hn[tid]      = (a - mu) * rstd * gam[tid]      + bet[tid];
    s_hn[64 + tid] = (d - mu) * rstd * gam[64 + tid] + bet[64 + tid];
  }
  __syncthreads();

  // ---- FC head ----
  if (tid < Cn) {
    float acc = fcb[tid];
    const float* wp = fcw + tid * Hn;
#pragma unroll 4
    for (int k = 0; k < Hn; ++k) acc += s_hn[k] * wp[k];
    out[(size_t)b * Cn + tid] = acc;
  }
}

extern "C" void kernel_launch(void* const* d_in, const int* in_sizes, int n_in,
                              void* d_out, int out_size, void* d_ws, size_t ws_size,
                              hipStream_t stream) {
  (void)in_sizes; (void)n_in; (void)d_ws; (void)ws_size; (void)out_size;
  lstm2_fused<<<dim3(Bn), dim3(512), 0, stream>>>(
      (const float*)d_in[0],  (const int*)d_in[1],
      (const float*)d_in[2],  (const float*)d_in[3],
      (const float*)d_in[4],  (const float*)d_in[5],
      (const float*)d_in[6],  (const float*)d_in[7],
      (const float*)d_in[8],  (const float*)d_in[9],
      (const float*)d_in[10], (const float*)d_in[11],
      (const float*)d_in[12], (const float*)d_in[13],
      (float*)d_out);
}